// Round 13
// baseline (157.046 us; speedup 1.0000x reference)
//
#include <hip/hip_runtime.h>

#define XOR16(v)     __shfl_xor((v), 16, 64)
#define FENCE() asm volatile("" ::: "memory")
#define SB() __builtin_amdgcn_sched_barrier(0)

// per-item LDS layout (dwords). 15-col matrices at row stride 20.
// 4 independent waves per 256-thread block (NO barriers); each wave owns
// 2 items in its own LDS quarter; 32 lanes/item: lane (r,h) owns columns
// [8h..8h+7] of row r. LDS 8*1236*4 = 39552 B -> 4 blocks/CU = 16 waves/CU.
#define STR    1236
#define OFF_M1    0   // P -> Pp -> Pn   (15 rows x 20)
#define OFF_M2  300   // A -> IKC        (15 rows x 20)
#define OFF_C   600   // C               (6 rows x 16)
#define OFF_S4  696   // B -> PpCt -> K  (15 rows x 8; dword6 = xp stage)
#define OFF_Q   816   // Q, then S       (6 rows x 8)
#define OFF_R   864   // R               (6 rows x 8)
#define OFF_VX  912   // x vector, then ev (16)
#define OFF_VU  928   // u vector (8)
#define OFF_M3  936   // Y -> T3         (15 rows x 20)

__device__ __forceinline__ float dot15(const float* Lr, const float* v) {
    float4 x0 = *(const float4*)(Lr);
    float4 x1 = *(const float4*)(Lr + 4);
    float4 x2 = *(const float4*)(Lr + 8);
    float4 x3 = *(const float4*)(Lr + 12);
    return v[0]*x0.x + v[1]*x0.y + v[2]*x0.z + v[3]*x0.w
         + v[4]*x1.x + v[5]*x1.y + v[6]*x1.z + v[7]*x1.w
         + v[8]*x2.x + v[9]*x2.y + v[10]*x2.z + v[11]*x2.w
         + v[12]*x3.x + v[13]*x3.y + v[14]*x3.z;
}
__device__ __forceinline__ void rd15(const float* Lr, float* v) {
    float4 x0 = *(const float4*)(Lr);
    float4 x1 = *(const float4*)(Lr + 4);
    float4 x2 = *(const float4*)(Lr + 8);
    float4 x3 = *(const float4*)(Lr + 12);
    v[0]=x0.x; v[1]=x0.y; v[2]=x0.z; v[3]=x0.w;
    v[4]=x1.x; v[5]=x1.y; v[6]=x1.z; v[7]=x1.w;
    v[8]=x2.x; v[9]=x2.y; v[10]=x2.z; v[11]=x2.w;
    v[12]=x3.x; v[13]=x3.y; v[14]=x3.z;
}
__device__ __forceinline__ float dot8(const float* Lr, const float* v) {
    float4 x0 = *(const float4*)(Lr);
    float4 x1 = *(const float4*)(Lr + 4);
    return v[0]*x0.x + v[1]*x0.y + v[2]*x0.z + v[3]*x0.w
         + v[4]*x1.x + v[5]*x1.y + v[6]*x1.z + v[7]*x1.w;
}
__device__ __forceinline__ void rd8(const float* Lr, float* v) {
    float4 x0 = *(const float4*)(Lr);
    float4 x1 = *(const float4*)(Lr + 4);
    v[0]=x0.x; v[1]=x0.y; v[2]=x0.z; v[3]=x0.w;
    v[4]=x1.x; v[5]=x1.y; v[6]=x1.z; v[7]=x1.w;
}
__device__ __forceinline__ void axpy8(const float* Lr, float s, float* acc) {
    float4 x0 = *(const float4*)(Lr);
    float4 x1 = *(const float4*)(Lr + 4);
    acc[0]+=s*x0.x; acc[1]+=s*x0.y; acc[2]+=s*x0.z; acc[3]+=s*x0.w;
    acc[4]+=s*x1.x; acc[5]+=s*x1.y; acc[6]+=s*x1.z; acc[7]+=s*x1.w;
}
__device__ __forceinline__ void wrow8(float* Lr, const float* v) {
    *(float4*)(Lr)     = make_float4(v[0],v[1],v[2],v[3]);
    *(float4*)(Lr + 4) = make_float4(v[4],v[5],v[6],v[7]);
}
__device__ __forceinline__ float dot6(const float* Lr, const float* v) {
    float4 x0 = *(const float4*)(Lr);
    float2 x1 = *(const float2*)(Lr + 4);
    return v[0]*x0.x + v[1]*x0.y + v[2]*x0.z + v[3]*x0.w + v[4]*x1.x + v[5]*x1.y;
}
__device__ __forceinline__ void rd6(const float* Lr, float* v) {
    float4 x0 = *(const float4*)(Lr);
    float2 x1 = *(const float2*)(Lr + 4);
    v[0]=x0.x; v[1]=x0.y; v[2]=x0.z; v[3]=x0.w; v[4]=x1.x; v[5]=x1.y;
}
__device__ __forceinline__ void wrow6(float* Lr, const float* v) {
    *(float4*)(Lr)     = make_float4(v[0],v[1],v[2],v[3]);
    *(float2*)(Lr + 4) = make_float2(v[4],v[5]);
}

__global__
__attribute__((amdgpu_flat_work_group_size(256, 256)))
__attribute__((amdgpu_waves_per_eu(2, 4)))
void ekf_kernel(
    const float* __restrict__ g_state, const float* __restrict__ g_obs,
    const float* __restrict__ g_u,     const float* __restrict__ g_P,
    const float* __restrict__ g_A,     const float* __restrict__ g_B,
    const float* __restrict__ g_C,     const float* __restrict__ g_D,
    const float* __restrict__ g_c1,    const float* __restrict__ g_c2,
    const float* __restrict__ g_Q,     const float* __restrict__ g_R,
    float* __restrict__ o_xp, float* __restrict__ o_Pn, int bn)
{
    __shared__ __align__(16) float lds[8 * STR];
    const int tid = threadIdx.x & 63;          // lane within wave
    const int wid = threadIdx.x >> 6;          // wave within block (independent)
    const int ib0 = blockIdx.x * 8 + wid * 2;  // this wave's 2 items
    if (ib0 >= bn) return;
    const int nIt = min(2, bn - ib0);
    float* ldsw = lds + wid * 2 * STR;         // this wave's LDS quarter

    const int g   = tid >> 5;           // item within wave
    const int s   = tid & 31;           // lane within item
    const int r   = s & 15;             // row
    const int h   = s >> 4;             // column half (0: 0-7, 1: 8-15)
    const int j0  = 8 * h;
    const int itc = ib0 + ((g < nIt) ? g : (nIt - 1));
    const int rc  = r < 15 ? r : 14;
    const int rc6 = r < 6 ? r : 5;
    float* L = ldsw + g * STR;

    // ================= staging: ALL global loads issued up-front ==========
    const float* gp = g_P + (size_t)ib0 * 225;
    const float* ga = g_A + (size_t)ib0 * 225;
    const float* gc = g_C + (size_t)ib0 * 90;
    const float* gb = g_B + (size_t)ib0 * 90;
    const float* gq = g_Q + (size_t)ib0 * 36;
    const float* gr = g_R + (size_t)ib0 * 36;
    const float* gs = g_state + (size_t)ib0 * 15;
    const float* gu = g_u + (size_t)ib0 * 6;
    const int limPA = nIt * 225, limCB = nIt * 90, limQR = nIt * 36;
    const int limS = nIt * 15, limU = nIt * 6;

    float vP[8], vA[8], vC[3], vB[3], vQ[2], vR[2], vS, vU;
    #pragma unroll
    for (int t = 0; t < 8; ++t) {
        int i = min(tid + t * 64, limPA - 1);
        vP[t] = gp[i]; vA[t] = ga[i];
    }
    #pragma unroll
    for (int t = 0; t < 3; ++t) {
        int i = min(tid + t * 64, limCB - 1);
        vC[t] = gc[i]; vB[t] = gb[i];
    }
    #pragma unroll
    for (int t = 0; t < 2; ++t) {
        int i = min(tid + t * 64, limQR - 1);
        vQ[t] = gq[i]; vR[t] = gr[i];
    }
    vS = gs[min(tid, limS - 1)];
    vU = gu[min(tid, limU - 1)];
    // phase-1 per-lane scalars, issued now too
    float c1v  = g_c1[(size_t)itc * 15 + rc];
    float obsv = g_obs[(size_t)itc * 6 + rc6];
    float c2v  = g_c2[(size_t)itc * 6 + rc6];
    const float* Db = g_D + (size_t)itc * 36 + rc6 * 6;
    float dd0 = Db[0], dd1 = Db[1], dd2 = Db[2], dd3 = Db[3], dd4 = Db[4], dd5 = Db[5];

    // ---- LDS write phase ----
    #pragma unroll
    for (int t = 0; t < 8; ++t) {
        int i = tid + t * 64;
        if (i < 450) {
            int it = i / 225, idx = i - it * 225;
            int rw = idx / 15, j = idx - rw * 15;
            ldsw[it * STR + OFF_M1 + rw * 20 + j] = vP[t];
            ldsw[it * STR + OFF_M2 + rw * 20 + j] = vA[t];
        }
    }
    #pragma unroll
    for (int t = 0; t < 3; ++t) {
        int i = tid + t * 64;
        if (i < 180) {
            int it = i / 90, idx = i - it * 90;
            int rw = idx / 15, j = idx - rw * 15;
            ldsw[it * STR + OFF_C + rw * 16 + j] = vC[t];
            int rb = idx / 6, jb = idx - rb * 6;
            ldsw[it * STR + OFF_S4 + rb * 8 + jb] = vB[t];
        }
    }
    #pragma unroll
    for (int t = 0; t < 2; ++t) {
        int i = tid + t * 64;
        if (i < 72) {
            int it = i / 36, idx = i - it * 36;
            int rw = idx / 6, j = idx - rw * 6;
            ldsw[it * STR + OFF_Q + rw * 8 + j] = vQ[t];
            ldsw[it * STR + OFF_R + rw * 8 + j] = vR[t];
        }
    }
    if (tid < 30) { int it = tid / 15, rw = tid - it * 15; ldsw[it * STR + OFF_VX + rw] = vS; }
    if (tid < 12) { int it = tid / 6,  rw = tid - it * 6;  ldsw[it * STR + OFF_VU + rw] = vU; }
    // zero pad column 15 (read by h=1 8-wide ops)
    if (r < 15) { L[OFF_M1 + r * 20 + 15] = 0.f; L[OFF_M2 + r * 20 + 15] = 0.f; }
    if (s < 6)  L[OFF_C + s * 16 + 15] = 0.f;
    if (s == 15) L[OFF_VX + 15] = 0.f;
    FENCE(); SB();

    // ================= phase 1: xp0, ev (half-dots + xor-sum) =============
    float xp;
    {
        float xh[8]; rd8(L + OFF_VX + j0, xh);
        float u6[6]; rd6(L + OFF_VU, u6);
        float xpp =  dot8(L + OFF_M2 + rc * 20 + j0, xh);
        float evp = -dot8(L + OFF_C + rc6 * 16 + j0, xh);
        if (h == 0) {
            xpp += c1v + dot6(L + OFF_S4 + rc * 8, u6);
            evp += obsv - c2v
                 - (dd0*u6[0] + dd1*u6[1] + dd2*u6[2]
                  + dd3*u6[3] + dd4*u6[4] + dd5*u6[5]);
        }
        xp = xpp + XOR16(xpp);
        float ev = evp + XOR16(evp);
        FENCE();
        if (h == 0 && r < 6) L[OFF_VX + r] = ev;   // stage ev (x dead)
        FENCE();
    }
    SB();

    // ================= phase 2: Pp = A P A^T + B Q B^T ====================
    float pp8[8];
    {   // Y = A @ P  (my 8 cols)
        float af[15]; rd15(L + OFF_M2 + rc * 20, af);
        float y8[8];
        #pragma unroll
        for (int j = 0; j < 8; ++j) y8[j] = 0.f;
        #define YK(k) axpy8(L + OFF_M1 + (k)*20 + j0, af[(k)], y8)
        YK(0); YK(1); YK(2); YK(3); YK(4); SB();
        YK(5); YK(6); YK(7); YK(8); YK(9); SB();
        YK(10); YK(11); YK(12); YK(13); YK(14); SB();
        FENCE();
        if (r < 15) wrow8(L + OFF_M3 + rc * 20 + j0, y8);   // Y -> M3
        FENCE(); SB();
    }
    {   // Pp = Y @ A^T  (full y row from M3, A rows broadcast)
        float yf[15]; rd15(L + OFF_M3 + rc * 20, yf);
        #define PPJ(j) pp8[(j)] = ((j0 + (j)) < 15) ? dot15(L + OFF_M2 + (j0 + (j))*20, yf) : 0.f
        PPJ(0); PPJ(1); PPJ(2); PPJ(3); SB();
        PPJ(4); PPJ(5); PPJ(6); PPJ(7); SB();
    }
    {   // Z = B @ Q (row r), Pp += Z @ B^T
        float bf[6]; rd6(L + OFF_S4 + rc * 8, bf);
        float z[6];
        #pragma unroll
        for (int j = 0; j < 6; ++j) z[j] = 0.f;
        #define ZK(k) do { float qk[6]; rd6(L + OFF_Q + (k)*8, qk); \
            z[0]+=bf[(k)]*qk[0]; z[1]+=bf[(k)]*qk[1]; z[2]+=bf[(k)]*qk[2]; \
            z[3]+=bf[(k)]*qk[3]; z[4]+=bf[(k)]*qk[4]; z[5]+=bf[(k)]*qk[5]; } while(0)
        ZK(0); ZK(1); ZK(2); SB(); ZK(3); ZK(4); ZK(5); SB();
        #define PBJ(j) if ((j0 + (j)) < 15) pp8[(j)] += dot6(L + OFF_S4 + (j0 + (j))*8, z)
        PBJ(0); PBJ(1); PBJ(2); PBJ(3); SB(); PBJ(4); PBJ(5); PBJ(6); PBJ(7); SB();
    }
    FENCE();
    if (r < 15) wrow8(L + OFF_M1 + rc * 20 + j0, pp8);      // Pp -> M1 (P dead)
    FENCE(); SB();

    // ================= phase 3: K (Cholesky in registers) =================
    float ppct[6];
    {   // PpCt partial over my k-half (pp8 = my Pp row half), xor-sum to full
        #define PCJ(c) ppct[(c)] = dot8(L + OFF_C + (c)*16 + j0, pp8)
        PCJ(0); PCJ(1); PCJ(2); SB(); PCJ(3); PCJ(4); PCJ(5); SB();
        #pragma unroll
        for (int c = 0; c < 6; ++c) ppct[c] += XOR16(ppct[c]);
    }
    FENCE();
    if (h == 0 && r < 15) wrow6(L + OFF_S4 + r * 8, ppct);  // PpCt -> S4 (B dead)
    FENCE(); SB();

    float kk[6];
    {
        // S = C @ PpCt + R, distributed over k-halves
        float sm[6];
        #pragma unroll
        for (int c = 0; c < 6; ++c) sm[c] = 0.f;
        {
            float ch[8]; rd8(L + OFF_C + rc6 * 16 + j0, ch);
            #define SAK(k) do { float pr[6]; rd6(L + OFF_S4 + (j0 + (k))*8, pr); \
                float cv = ch[(k)]; \
                sm[0]+=cv*pr[0]; sm[1]+=cv*pr[1]; sm[2]+=cv*pr[2]; \
                sm[3]+=cv*pr[3]; sm[4]+=cv*pr[4]; sm[5]+=cv*pr[5]; } while(0)
            SAK(0); SAK(1); SAK(2); SAK(3); SB();
            SAK(4); SAK(5); SAK(6); SAK(7); SB();
        }
        #pragma unroll
        for (int c = 0; c < 6; ++c) sm[c] += XOR16(sm[c]);
        if (h == 0 && r < 6) {
            float rr6[6]; rd6(L + OFF_R + r * 8, rr6);
            float srow[6];
            #pragma unroll
            for (int c = 0; c < 6; ++c) srow[c] = sm[c] + rr6[c];
            wrow6(L + OFF_Q + r * 8, srow);                 // S -> Q region (Q dead)
        }
        FENCE(); SB();

        // uniform broadcast read of S (lower triangle used)
        float r0[6], r1[6], r2[6], r3[6], r4[6], r5[6];
        rd6(L + OFF_Q + 0*8, r0); rd6(L + OFF_Q + 1*8, r1); rd6(L + OFF_Q + 2*8, r2); SB();
        rd6(L + OFF_Q + 3*8, r3); rd6(L + OFF_Q + 4*8, r4); rd6(L + OFF_Q + 5*8, r5); SB();

        // Cholesky S = L L^T (registers only; S SPD, diag >= 0.1)
        float l00 = sqrtf(r0[0]);                 float i0 = 1.f / l00;
        float l10 = r1[0]*i0, l20 = r2[0]*i0, l30 = r3[0]*i0, l40 = r4[0]*i0, l50 = r5[0]*i0;
        float l11 = sqrtf(r1[1] - l10*l10);       float i1 = 1.f / l11;
        float l21 = (r2[1] - l20*l10)*i1;
        float l31 = (r3[1] - l30*l10)*i1;
        float l41 = (r4[1] - l40*l10)*i1;
        float l51 = (r5[1] - l50*l10)*i1;
        float l22 = sqrtf(r2[2] - l20*l20 - l21*l21); float i2 = 1.f / l22;
        float l32 = (r3[2] - l30*l20 - l31*l21)*i2;
        float l42 = (r4[2] - l40*l20 - l41*l21)*i2;
        float l52 = (r5[2] - l50*l20 - l51*l21)*i2;
        float l33 = sqrtf(r3[3] - l30*l30 - l31*l31 - l32*l32); float i3 = 1.f / l33;
        float l43 = (r4[3] - l40*l30 - l41*l31 - l42*l32)*i3;
        float l53 = (r5[3] - l50*l30 - l51*l31 - l52*l32)*i3;
        float l44 = sqrtf(r4[4] - l40*l40 - l41*l41 - l42*l42 - l43*l43); float i4 = 1.f / l44;
        float l54 = (r5[4] - l50*l40 - l51*l41 - l52*l42 - l53*l43)*i4;
        float l55 = sqrtf(r5[5] - l50*l50 - l51*l51 - l52*l52 - l53*l53 - l54*l54);
        float i5 = 1.f / l55;

        // solve S x = ppct  (forward then backward); kk = x = K row rc
        float y0 =  ppct[0]*i0;
        float y1 = (ppct[1] - l10*y0)*i1;
        float y2 = (ppct[2] - l20*y0 - l21*y1)*i2;
        float y3 = (ppct[3] - l30*y0 - l31*y1 - l32*y2)*i3;
        float y4 = (ppct[4] - l40*y0 - l41*y1 - l42*y2 - l43*y3)*i4;
        float y5 = (ppct[5] - l50*y0 - l51*y1 - l52*y2 - l53*y3 - l54*y4)*i5;
        kk[5] =  y5*i5;
        kk[4] = (y4 - l54*kk[5])*i4;
        kk[3] = (y3 - l43*kk[4] - l53*kk[5])*i3;
        kk[2] = (y2 - l32*kk[3] - l42*kk[4] - l52*kk[5])*i2;
        kk[1] = (y1 - l21*kk[2] - l31*kk[3] - l41*kk[4] - l51*kk[5])*i1;
        kk[0] = (y0 - l10*kk[1] - l20*kk[2] - l30*kk[3] - l40*kk[4] - l50*kk[5])*i0;
    }
    FENCE();
    if (h == 0 && r < 15) wrow6(L + OFF_S4 + r * 8, kk);    // K -> S4 (PpCt dead)
    FENCE();
    {   // xp += K e  (ev staged in OFF_VX)
        float e6[6]; rd6(L + OFF_VX, e6);
        xp += kk[0]*e6[0] + kk[1]*e6[1] + kk[2]*e6[2]
            + kk[3]*e6[3] + kk[4]*e6[4] + kk[5]*e6[5];
    }
    SB();

    // ================= phase 4: Pn = IKC Pp IKC^T + K R K^T ===============
    float pn8[8];
    {
        float ikc8[8];
        #pragma unroll
        for (int j = 0; j < 8; ++j) ikc8[j] = (rc == j0 + j) ? 1.f : 0.f;
        #define IKK(k) do { const float* Ck = L + OFF_C + (k)*16 + j0; \
            float4 v0 = *(const float4*)(Ck); float4 v1 = *(const float4*)(Ck + 4); \
            float m = kk[(k)]; \
            ikc8[0]-=m*v0.x; ikc8[1]-=m*v0.y; ikc8[2]-=m*v0.z; ikc8[3]-=m*v0.w; \
            ikc8[4]-=m*v1.x; ikc8[5]-=m*v1.y; ikc8[6]-=m*v1.z; ikc8[7]-=m*v1.w; } while(0)
        IKK(0); IKK(1); IKK(2); SB(); IKK(3); IKK(4); IKK(5); SB();
        FENCE();
        if (r < 15) wrow8(L + OFF_M2 + rc * 20 + j0, ikc8); // IKC -> M2 (A dead)
        FENCE(); SB();
    }
    {   // T3 = IKC @ Pp  (my 8 cols)
        float ikf[15]; rd15(L + OFF_M2 + rc * 20, ikf);
        float t38[8];
        #pragma unroll
        for (int j = 0; j < 8; ++j) t38[j] = 0.f;
        #define TK(k) axpy8(L + OFF_M1 + (k)*20 + j0, ikf[(k)], t38)
        TK(0); TK(1); TK(2); TK(3); TK(4); SB();
        TK(5); TK(6); TK(7); TK(8); TK(9); SB();
        TK(10); TK(11); TK(12); TK(13); TK(14); SB();
        FENCE();
        if (r < 15) wrow8(L + OFF_M3 + rc * 20 + j0, t38);  // T3 -> M3 (Y dead)
        FENCE(); SB();
    }
    {   // Pn = T3 @ IKC^T
        float tf[15]; rd15(L + OFF_M3 + rc * 20, tf);
        #define PNJ(j) pn8[(j)] = ((j0 + (j)) < 15) ? dot15(L + OFF_M2 + (j0 + (j))*20, tf) : 0.f
        PNJ(0); PNJ(1); PNJ(2); PNJ(3); SB();
        PNJ(4); PNJ(5); PNJ(6); PNJ(7); SB();
    }
    {   // KR = K @ R (row rc), Pn += KR @ K^T
        float kr[6];
        #pragma unroll
        for (int j = 0; j < 6; ++j) kr[j] = 0.f;
        #define KRK(k) do { float rk[6]; rd6(L + OFF_R + (k)*8, rk); \
            kr[0]+=kk[(k)]*rk[0]; kr[1]+=kk[(k)]*rk[1]; kr[2]+=kk[(k)]*rk[2]; \
            kr[3]+=kk[(k)]*rk[3]; kr[4]+=kk[(k)]*rk[4]; kr[5]+=kk[(k)]*rk[5]; } while(0)
        KRK(0); KRK(1); KRK(2); SB(); KRK(3); KRK(4); KRK(5); SB();
        #define PKJ(j) if ((j0 + (j)) < 15) pn8[(j)] += dot6(L + OFF_S4 + (j0 + (j))*8, kr)
        PKJ(0); PKJ(1); PKJ(2); PKJ(3); SB(); PKJ(4); PKJ(5); PKJ(6); PKJ(7); SB();
    }

    // ---- stage results: Pn -> M1, xp -> S4 dword 6 ----
    FENCE();
    if (r < 15) {
        wrow8(L + OFF_M1 + rc * 20 + j0, pn8);
        if (h == 0) L[OFF_S4 + r * 8 + 6] = xp;
    }
    FENCE(); SB();

    // ---- coalesced stores (unrolled: LDS reads pipelined, then stores) ----
    {
        float* gpn = o_Pn + (size_t)ib0 * 225;
        float sP[8];
        #pragma unroll
        for (int t = 0; t < 8; ++t) {
            int i = min(tid + t * 64, 449);
            int it = i / 225, idx = i - it * 225;
            int rw = idx / 15, j = idx - rw * 15;
            sP[t] = ldsw[it * STR + OFF_M1 + rw * 20 + j];
        }
        #pragma unroll
        for (int t = 0; t < 8; ++t) {
            int i = tid + t * 64;
            if (i < limPA) gpn[i] = sP[t];
        }
        float* gxp = o_xp + (size_t)ib0 * 15;
        if (tid < limS) {
            int it = tid / 15, rw = tid - it * 15;
            gxp[tid] = ldsw[it * STR + OFF_S4 + rw * 8 + 6];
        }
    }
}

extern "C" void kernel_launch(void* const* d_in, const int* in_sizes, int n_in,
                              void* d_out, int out_size, void* d_ws, size_t ws_size,
                              hipStream_t stream) {
    const float* g_state = (const float*)d_in[0];
    const float* g_obs   = (const float*)d_in[1];
    const float* g_u     = (const float*)d_in[2];
    const float* g_P     = (const float*)d_in[3];
    const float* g_A     = (const float*)d_in[4];
    const float* g_B     = (const float*)d_in[5];
    const float* g_C     = (const float*)d_in[6];
    const float* g_D     = (const float*)d_in[7];
    const float* g_c1    = (const float*)d_in[8];
    const float* g_c2    = (const float*)d_in[9];
    const float* g_Q     = (const float*)d_in[10];
    const float* g_R     = (const float*)d_in[11];

    const int bn = in_sizes[0] / 15;
    float* o_xp = (float*)d_out;
    float* o_pn = o_xp + (size_t)bn * 15;

    const int blocks = (bn + 7) / 8;   // 8 items per 256-thread block (4 indep waves)
    ekf_kernel<<<blocks, 256, 0, stream>>>(
        g_state, g_obs, g_u, g_P, g_A, g_B, g_C, g_D, g_c1, g_c2, g_Q, g_R,
        o_xp, o_pn, bn);
}

// Round 14
// 110.564 us; speedup vs baseline: 1.4204x; 1.4204x over previous
//
#include <hip/hip_runtime.h>

#define XOR16(v)     __shfl_xor((v), 16, 64)
#define FENCE() asm volatile("" ::: "memory")
#define SB() __builtin_amdgcn_sched_barrier(0)

// per-item LDS layout (dwords). 15-col matrices at row stride 20.
// 2 items per 64-thread (1-wave) block; 32 lanes/item: lane (r,h) owns
// columns [8h..8h+7] of row r. LDS 2*1236*4 = 9888 B.
#define STR    1236
#define OFF_M1    0   // P -> Pp -> Pn   (15 rows x 20)
#define OFF_M2  300   // A               (15 rows x 20)
#define OFF_C   600   // C               (6 rows x 16, col15 zero pad)
#define OFF_S4  696   // B               (15 rows x 8; dword6 = xp stage)
#define OFF_Q   816   // Q, then S       (6 rows x 8)
#define OFF_R   864   // R               (6 rows x 8)
#define OFF_VX  912   // x vector, then ev (16)
#define OFF_VU  928   // u vector (8)
#define OFF_M3  936   // Y (ph2); then per row k (stride 20): [0..5]=PpCt, [8..13]=K

__device__ __forceinline__ float dot15(const float* Lr, const float* v) {
    float4 x0 = *(const float4*)(Lr);
    float4 x1 = *(const float4*)(Lr + 4);
    float4 x2 = *(const float4*)(Lr + 8);
    float4 x3 = *(const float4*)(Lr + 12);
    return v[0]*x0.x + v[1]*x0.y + v[2]*x0.z + v[3]*x0.w
         + v[4]*x1.x + v[5]*x1.y + v[6]*x1.z + v[7]*x1.w
         + v[8]*x2.x + v[9]*x2.y + v[10]*x2.z + v[11]*x2.w
         + v[12]*x3.x + v[13]*x3.y + v[14]*x3.z;
}
__device__ __forceinline__ void rd15(const float* Lr, float* v) {
    float4 x0 = *(const float4*)(Lr);
    float4 x1 = *(const float4*)(Lr + 4);
    float4 x2 = *(const float4*)(Lr + 8);
    float4 x3 = *(const float4*)(Lr + 12);
    v[0]=x0.x; v[1]=x0.y; v[2]=x0.z; v[3]=x0.w;
    v[4]=x1.x; v[5]=x1.y; v[6]=x1.z; v[7]=x1.w;
    v[8]=x2.x; v[9]=x2.y; v[10]=x2.z; v[11]=x2.w;
    v[12]=x3.x; v[13]=x3.y; v[14]=x3.z;
}
__device__ __forceinline__ float dot8(const float* Lr, const float* v) {
    float4 x0 = *(const float4*)(Lr);
    float4 x1 = *(const float4*)(Lr + 4);
    return v[0]*x0.x + v[1]*x0.y + v[2]*x0.z + v[3]*x0.w
         + v[4]*x1.x + v[5]*x1.y + v[6]*x1.z + v[7]*x1.w;
}
__device__ __forceinline__ void rd8(const float* Lr, float* v) {
    float4 x0 = *(const float4*)(Lr);
    float4 x1 = *(const float4*)(Lr + 4);
    v[0]=x0.x; v[1]=x0.y; v[2]=x0.z; v[3]=x0.w;
    v[4]=x1.x; v[5]=x1.y; v[6]=x1.z; v[7]=x1.w;
}
__device__ __forceinline__ void axpy8(const float* Lr, float s, float* acc) {
    float4 x0 = *(const float4*)(Lr);
    float4 x1 = *(const float4*)(Lr + 4);
    acc[0]+=s*x0.x; acc[1]+=s*x0.y; acc[2]+=s*x0.z; acc[3]+=s*x0.w;
    acc[4]+=s*x1.x; acc[5]+=s*x1.y; acc[6]+=s*x1.z; acc[7]+=s*x1.w;
}
__device__ __forceinline__ void wrow8(float* Lr, const float* v) {
    *(float4*)(Lr)     = make_float4(v[0],v[1],v[2],v[3]);
    *(float4*)(Lr + 4) = make_float4(v[4],v[5],v[6],v[7]);
}
__device__ __forceinline__ float dot6(const float* Lr, const float* v) {
    float4 x0 = *(const float4*)(Lr);
    float2 x1 = *(const float2*)(Lr + 4);
    return v[0]*x0.x + v[1]*x0.y + v[2]*x0.z + v[3]*x0.w + v[4]*x1.x + v[5]*x1.y;
}
__device__ __forceinline__ void rd6(const float* Lr, float* v) {
    float4 x0 = *(const float4*)(Lr);
    float2 x1 = *(const float2*)(Lr + 4);
    v[0]=x0.x; v[1]=x0.y; v[2]=x0.z; v[3]=x0.w; v[4]=x1.x; v[5]=x1.y;
}
__device__ __forceinline__ void wrow6(float* Lr, const float* v) {
    *(float4*)(Lr)     = make_float4(v[0],v[1],v[2],v[3]);
    *(float2*)(Lr + 4) = make_float2(v[4],v[5]);
}

__global__
__attribute__((amdgpu_flat_work_group_size(64, 64)))
__attribute__((amdgpu_waves_per_eu(2, 4)))
void ekf_kernel(
    const float* __restrict__ g_state, const float* __restrict__ g_obs,
    const float* __restrict__ g_u,     const float* __restrict__ g_P,
    const float* __restrict__ g_A,     const float* __restrict__ g_B,
    const float* __restrict__ g_C,     const float* __restrict__ g_D,
    const float* __restrict__ g_c1,    const float* __restrict__ g_c2,
    const float* __restrict__ g_Q,     const float* __restrict__ g_R,
    float* __restrict__ o_xp, float* __restrict__ o_Pn, int bn)
{
    __shared__ __align__(16) float lds[2 * STR];
    const int tid = threadIdx.x;        // 64 threads = ONE wave = 2 items
    const int ib0 = blockIdx.x * 2;
    const int nIt = min(2, bn - ib0);

    const int g   = tid >> 5;           // item within block
    const int s   = tid & 31;           // lane within item
    const int r   = s & 15;             // row
    const int h   = s >> 4;             // column half (0: 0-7, 1: 8-15)
    const int j0  = 8 * h;
    const int itc = ib0 + ((g < nIt) ? g : (nIt - 1));
    const int rc  = r < 15 ? r : 14;
    const int rc6 = r < 6 ? r : 5;
    float* L = lds + g * STR;

    // ================= staging: ALL global loads issued up-front ==========
    const float* gp = g_P + (size_t)ib0 * 225;
    const float* ga = g_A + (size_t)ib0 * 225;
    const float* gc = g_C + (size_t)ib0 * 90;
    const float* gb = g_B + (size_t)ib0 * 90;
    const float* gq = g_Q + (size_t)ib0 * 36;
    const float* gr = g_R + (size_t)ib0 * 36;
    const float* gs = g_state + (size_t)ib0 * 15;
    const float* gu = g_u + (size_t)ib0 * 6;
    const int limPA = nIt * 225, limCB = nIt * 90, limQR = nIt * 36;
    const int limS = nIt * 15, limU = nIt * 6;

    float vP[8], vA[8], vC[3], vB[3], vQ[2], vR[2], vS, vU;
    #pragma unroll
    for (int t = 0; t < 8; ++t) {
        int i = min(tid + t * 64, limPA - 1);
        vP[t] = gp[i]; vA[t] = ga[i];
    }
    #pragma unroll
    for (int t = 0; t < 3; ++t) {
        int i = min(tid + t * 64, limCB - 1);
        vC[t] = gc[i]; vB[t] = gb[i];
    }
    #pragma unroll
    for (int t = 0; t < 2; ++t) {
        int i = min(tid + t * 64, limQR - 1);
        vQ[t] = gq[i]; vR[t] = gr[i];
    }
    vS = gs[min(tid, limS - 1)];
    vU = gu[min(tid, limU - 1)];
    // phase-1 per-lane scalars, issued now too
    float c1v  = g_c1[(size_t)itc * 15 + rc];
    float obsv = g_obs[(size_t)itc * 6 + rc6];
    float c2v  = g_c2[(size_t)itc * 6 + rc6];
    const float* Db = g_D + (size_t)itc * 36 + rc6 * 6;
    float dd0 = Db[0], dd1 = Db[1], dd2 = Db[2], dd3 = Db[3], dd4 = Db[4], dd5 = Db[5];

    // ---- LDS write phase ----
    #pragma unroll
    for (int t = 0; t < 8; ++t) {
        int i = tid + t * 64;
        if (i < 450) {
            int it = i / 225, idx = i - it * 225;
            int rw = idx / 15, j = idx - rw * 15;
            lds[it * STR + OFF_M1 + rw * 20 + j] = vP[t];
            lds[it * STR + OFF_M2 + rw * 20 + j] = vA[t];
        }
    }
    #pragma unroll
    for (int t = 0; t < 3; ++t) {
        int i = tid + t * 64;
        if (i < 180) {
            int it = i / 90, idx = i - it * 90;
            int rw = idx / 15, j = idx - rw * 15;
            lds[it * STR + OFF_C + rw * 16 + j] = vC[t];
            int rb = idx / 6, jb = idx - rb * 6;
            lds[it * STR + OFF_S4 + rb * 8 + jb] = vB[t];
        }
    }
    #pragma unroll
    for (int t = 0; t < 2; ++t) {
        int i = tid + t * 64;
        if (i < 72) {
            int it = i / 36, idx = i - it * 36;
            int rw = idx / 6, j = idx - rw * 6;
            lds[it * STR + OFF_Q + rw * 8 + j] = vQ[t];
            lds[it * STR + OFF_R + rw * 8 + j] = vR[t];
        }
    }
    if (tid < 30) { int it = tid / 15, rw = tid - it * 15; lds[it * STR + OFF_VX + rw] = vS; }
    if (tid < 12) { int it = tid / 6,  rw = tid - it * 6;  lds[it * STR + OFF_VU + rw] = vU; }
    // zero pad column 15 (read by h=1 8-wide ops)
    if (r < 15) { L[OFF_M1 + r * 20 + 15] = 0.f; L[OFF_M2 + r * 20 + 15] = 0.f; }
    if (s < 6)  L[OFF_C + s * 16 + 15] = 0.f;
    if (s == 15) L[OFF_VX + 15] = 0.f;
    FENCE(); SB();

    // ================= phase 1: xp0, ev (half-dots + xor-sum) =============
    float xp;
    {
        float xh[8]; rd8(L + OFF_VX + j0, xh);
        float u6[6]; rd6(L + OFF_VU, u6);
        float xpp =  dot8(L + OFF_M2 + rc * 20 + j0, xh);
        float evp = -dot8(L + OFF_C + rc6 * 16 + j0, xh);
        if (h == 0) {
            xpp += c1v + dot6(L + OFF_S4 + rc * 8, u6);
            evp += obsv - c2v
                 - (dd0*u6[0] + dd1*u6[1] + dd2*u6[2]
                  + dd3*u6[3] + dd4*u6[4] + dd5*u6[5]);
        }
        xp = xpp + XOR16(xpp);
        float ev = evp + XOR16(evp);
        FENCE();
        if (h == 0 && r < 6) L[OFF_VX + r] = ev;   // stage ev (x dead)
        FENCE();
    }
    SB();

    // ================= phase 2: Pp = A P A^T + B Q B^T ====================
    float pp8[8];
    {   // Y = A @ P  (my 8 cols)
        float af[15]; rd15(L + OFF_M2 + rc * 20, af);
        float y8[8];
        #pragma unroll
        for (int j = 0; j < 8; ++j) y8[j] = 0.f;
        #define YK(k) axpy8(L + OFF_M1 + (k)*20 + j0, af[(k)], y8)
        YK(0); YK(1); YK(2); YK(3); YK(4); SB();
        YK(5); YK(6); YK(7); YK(8); YK(9); SB();
        YK(10); YK(11); YK(12); YK(13); YK(14); SB();
        FENCE();
        if (r < 15) wrow8(L + OFF_M3 + rc * 20 + j0, y8);   // Y -> M3
        FENCE(); SB();
    }
    {   // Pp = Y @ A^T  (full y row from M3, A rows broadcast)
        float yf[15]; rd15(L + OFF_M3 + rc * 20, yf);
        #define PPJ(j) pp8[(j)] = ((j0 + (j)) < 15) ? dot15(L + OFF_M2 + (j0 + (j))*20, yf) : 0.f
        PPJ(0); PPJ(1); PPJ(2); PPJ(3); SB();
        PPJ(4); PPJ(5); PPJ(6); PPJ(7); SB();
    }
    {   // Z = B @ Q (row r), Pp += Z @ B^T
        float bf[6]; rd6(L + OFF_S4 + rc * 8, bf);
        float z[6];
        #pragma unroll
        for (int j = 0; j < 6; ++j) z[j] = 0.f;
        #define ZK(k) do { float qk[6]; rd6(L + OFF_Q + (k)*8, qk); \
            z[0]+=bf[(k)]*qk[0]; z[1]+=bf[(k)]*qk[1]; z[2]+=bf[(k)]*qk[2]; \
            z[3]+=bf[(k)]*qk[3]; z[4]+=bf[(k)]*qk[4]; z[5]+=bf[(k)]*qk[5]; } while(0)
        ZK(0); ZK(1); ZK(2); SB(); ZK(3); ZK(4); ZK(5); SB();
        #define PBJ(j) if ((j0 + (j)) < 15) pp8[(j)] += dot6(L + OFF_S4 + (j0 + (j))*8, z)
        PBJ(0); PBJ(1); PBJ(2); PBJ(3); SB(); PBJ(4); PBJ(5); PBJ(6); PBJ(7); SB();
    }
    FENCE();
    if (r < 15) wrow8(L + OFF_M1 + rc * 20 + j0, pp8);      // Pp -> M1 (P dead)
    FENCE(); SB();

    // ================= phase 3: K (Cholesky in registers) =================
    float ppct[6];
    {   // PpCt partial over my k-half (pp8 = my Pp row half), xor-sum to full
        #define PCJ(c) ppct[(c)] = dot8(L + OFF_C + (c)*16 + j0, pp8)
        PCJ(0); PCJ(1); PCJ(2); SB(); PCJ(3); PCJ(4); PCJ(5); SB();
        #pragma unroll
        for (int c = 0; c < 6; ++c) ppct[c] += XOR16(ppct[c]);
    }
    FENCE();
    if (h == 0 && r < 15) wrow6(L + OFF_M3 + r * 20, ppct); // PpCt -> M3[:, 0..5] (Y dead)
    FENCE(); SB();

    float kk[6];
    {
        // S = C @ PpCt + R, distributed over k-halves
        float sm[6];
        #pragma unroll
        for (int c = 0; c < 6; ++c) sm[c] = 0.f;
        {
            float ch[8]; rd8(L + OFF_C + rc6 * 16 + j0, ch);
            #define SAK(k) do { float pr[6]; rd6(L + OFF_M3 + min(j0 + (k), 14)*20, pr); \
                float cv = ch[(k)]; \
                sm[0]+=cv*pr[0]; sm[1]+=cv*pr[1]; sm[2]+=cv*pr[2]; \
                sm[3]+=cv*pr[3]; sm[4]+=cv*pr[4]; sm[5]+=cv*pr[5]; } while(0)
            SAK(0); SAK(1); SAK(2); SAK(3); SB();
            SAK(4); SAK(5); SAK(6); SAK(7); SB();
        }
        #pragma unroll
        for (int c = 0; c < 6; ++c) sm[c] += XOR16(sm[c]);
        if (h == 0 && r < 6) {
            float rr6[6]; rd6(L + OFF_R + r * 8, rr6);
            float srow[6];
            #pragma unroll
            for (int c = 0; c < 6; ++c) srow[c] = sm[c] + rr6[c];
            wrow6(L + OFF_Q + r * 8, srow);                 // S -> Q region (Q dead)
        }
        FENCE(); SB();

        // uniform broadcast read of S (lower triangle used)
        float r0[6], r1[6], r2[6], r3[6], r4[6], r5[6];
        rd6(L + OFF_Q + 0*8, r0); rd6(L + OFF_Q + 1*8, r1); rd6(L + OFF_Q + 2*8, r2); SB();
        rd6(L + OFF_Q + 3*8, r3); rd6(L + OFF_Q + 4*8, r4); rd6(L + OFF_Q + 5*8, r5); SB();

        // Cholesky S = L L^T (registers only; S SPD, diag >= 0.1)
        float l00 = sqrtf(r0[0]);                 float i0 = 1.f / l00;
        float l10 = r1[0]*i0, l20 = r2[0]*i0, l30 = r3[0]*i0, l40 = r4[0]*i0, l50 = r5[0]*i0;
        float l11 = sqrtf(r1[1] - l10*l10);       float i1 = 1.f / l11;
        float l21 = (r2[1] - l20*l10)*i1;
        float l31 = (r3[1] - l30*l10)*i1;
        float l41 = (r4[1] - l40*l10)*i1;
        float l51 = (r5[1] - l50*l10)*i1;
        float l22 = sqrtf(r2[2] - l20*l20 - l21*l21); float i2 = 1.f / l22;
        float l32 = (r3[2] - l30*l20 - l31*l21)*i2;
        float l42 = (r4[2] - l40*l20 - l41*l21)*i2;
        float l52 = (r5[2] - l50*l20 - l51*l21)*i2;
        float l33 = sqrtf(r3[3] - l30*l30 - l31*l31 - l32*l32); float i3 = 1.f / l33;
        float l43 = (r4[3] - l40*l30 - l41*l31 - l42*l32)*i3;
        float l53 = (r5[3] - l50*l30 - l51*l31 - l52*l32)*i3;
        float l44 = sqrtf(r4[4] - l40*l40 - l41*l41 - l42*l42 - l43*l43); float i4 = 1.f / l44;
        float l54 = (r5[4] - l50*l40 - l51*l41 - l52*l42 - l53*l43)*i4;
        float l55 = sqrtf(r5[5] - l50*l50 - l51*l51 - l52*l52 - l53*l53 - l54*l54);
        float i5 = 1.f / l55;

        // solve S x = ppct  (forward then backward); kk = x = K row rc
        float y0 =  ppct[0]*i0;
        float y1 = (ppct[1] - l10*y0)*i1;
        float y2 = (ppct[2] - l20*y0 - l21*y1)*i2;
        float y3 = (ppct[3] - l30*y0 - l31*y1 - l32*y2)*i3;
        float y4 = (ppct[4] - l40*y0 - l41*y1 - l42*y2 - l43*y3)*i4;
        float y5 = (ppct[5] - l50*y0 - l51*y1 - l52*y2 - l53*y3 - l54*y4)*i5;
        kk[5] =  y5*i5;
        kk[4] = (y4 - l54*kk[5])*i4;
        kk[3] = (y3 - l43*kk[4] - l53*kk[5])*i3;
        kk[2] = (y2 - l32*kk[3] - l42*kk[4] - l52*kk[5])*i2;
        kk[1] = (y1 - l21*kk[2] - l31*kk[3] - l41*kk[4] - l51*kk[5])*i1;
        kk[0] = (y0 - l10*kk[1] - l20*kk[2] - l30*kk[3] - l40*kk[4] - l50*kk[5])*i0;
    }
    FENCE();
    if (h == 0 && r < 15) wrow6(L + OFF_M3 + r * 20 + 8, kk);  // K -> M3[:, 8..13]
    FENCE();
    {   // xp += K e  (ev staged in OFF_VX)
        float e6[6]; rd6(L + OFF_VX, e6);
        xp += kk[0]*e6[0] + kk[1]*e6[1] + kk[2]*e6[2]
            + kk[3]*e6[3] + kk[4]*e6[4] + kk[5]*e6[5];
    }
    SB();

    // ===== phase 4 (refactored, Pp symmetric):
    //   T3 = Pp - K*PpCt^T          (regs: pp8, kk; reads PpCt rows)
    //   G  = T3*C^T                 (half-dot + xor-sum)
    //   Pn = T3 + (K*R - G)*K^T     (reads R rows, K rows)
    float pn8[8];
    {
        float t38[8];
        #define T3J(j) do { float pr[6]; rd6(L + OFF_M3 + min(j0 + (j), 14)*20, pr); \
            t38[(j)] = pp8[(j)] - (kk[0]*pr[0]+kk[1]*pr[1]+kk[2]*pr[2] \
                                  +kk[3]*pr[3]+kk[4]*pr[4]+kk[5]*pr[5]); } while(0)
        T3J(0); T3J(1); T3J(2); T3J(3); SB();
        T3J(4); T3J(5); T3J(6); T3J(7); SB();
        if (j0 + 7 >= 15) t38[7] = 0.f;   // h=1 col-15 tail (pad)

        // G = T3 C^T (partial over my k-half, xor-sum); C col15 pad = 0
        float w[6];
        #define GJ(c) w[(c)] = dot8(L + OFF_C + (c)*16 + j0, t38)
        GJ(0); GJ(1); GJ(2); SB(); GJ(3); GJ(4); GJ(5); SB();
        #pragma unroll
        for (int c = 0; c < 6; ++c) w[c] = -(w[c] + XOR16(w[c]));   // w = -G

        // w += K @ R  (row rc of K in regs)
        #define KRK(k) do { float rk[6]; rd6(L + OFF_R + (k)*8, rk); \
            w[0]+=kk[(k)]*rk[0]; w[1]+=kk[(k)]*rk[1]; w[2]+=kk[(k)]*rk[2]; \
            w[3]+=kk[(k)]*rk[3]; w[4]+=kk[(k)]*rk[4]; w[5]+=kk[(k)]*rk[5]; } while(0)
        KRK(0); KRK(1); KRK(2); SB(); KRK(3); KRK(4); KRK(5); SB();

        // Pn = T3 + w * K^T  (read K rows j0+j)
        #define PNJ(j) do { float krow[6]; rd6(L + OFF_M3 + min(j0 + (j), 14)*20 + 8, krow); \
            pn8[(j)] = t38[(j)] + (w[0]*krow[0]+w[1]*krow[1]+w[2]*krow[2] \
                                  +w[3]*krow[3]+w[4]*krow[4]+w[5]*krow[5]); } while(0)
        PNJ(0); PNJ(1); PNJ(2); PNJ(3); SB();
        PNJ(4); PNJ(5); PNJ(6); PNJ(7); SB();
        if (j0 + 7 >= 15) pn8[7] = 0.f;   // pad column store
    }

    // ---- stage results: Pn -> M1, xp -> S4 dword 6 ----
    FENCE();
    if (r < 15) {
        wrow8(L + OFF_M1 + rc * 20 + j0, pn8);
        if (h == 0) L[OFF_S4 + r * 8 + 6] = xp;
    }
    FENCE(); SB();

    // ---- coalesced stores (unrolled: LDS reads pipelined, then stores) ----
    {
        float* gpn = o_Pn + (size_t)ib0 * 225;
        float sP[8];
        #pragma unroll
        for (int t = 0; t < 8; ++t) {
            int i = min(tid + t * 64, 449);
            int it = i / 225, idx = i - it * 225;
            int rw = idx / 15, j = idx - rw * 15;
            sP[t] = lds[it * STR + OFF_M1 + rw * 20 + j];
        }
        #pragma unroll
        for (int t = 0; t < 8; ++t) {
            int i = tid + t * 64;
            if (i < limPA) gpn[i] = sP[t];
        }
        float* gxp = o_xp + (size_t)ib0 * 15;
        if (tid < limS) {
            int it = tid / 15, rw = tid - it * 15;
            gxp[tid] = lds[it * STR + OFF_S4 + rw * 8 + 6];
        }
    }
}

extern "C" void kernel_launch(void* const* d_in, const int* in_sizes, int n_in,
                              void* d_out, int out_size, void* d_ws, size_t ws_size,
                              hipStream_t stream) {
    const float* g_state = (const float*)d_in[0];
    const float* g_obs   = (const float*)d_in[1];
    const float* g_u     = (const float*)d_in[2];
    const float* g_P     = (const float*)d_in[3];
    const float* g_A     = (const float*)d_in[4];
    const float* g_B     = (const float*)d_in[5];
    const float* g_C     = (const float*)d_in[6];
    const float* g_D     = (const float*)d_in[7];
    const float* g_c1    = (const float*)d_in[8];
    const float* g_c2    = (const float*)d_in[9];
    const float* g_Q     = (const float*)d_in[10];
    const float* g_R     = (const float*)d_in[11];

    const int bn = in_sizes[0] / 15;
    float* o_xp = (float*)d_out;
    float* o_pn = o_xp + (size_t)bn * 15;

    const int blocks = (bn + 1) / 2;   // 2 items per 64-thread (1-wave) block
    ekf_kernel<<<blocks, 64, 0, stream>>>(
        g_state, g_obs, g_u, g_P, g_A, g_B, g_C, g_D, g_c1, g_c2, g_Q, g_R,
        o_xp, o_pn, bn);
}